// Round 10
// baseline (266.776 us; speedup 1.0000x reference)
//
#include <hip/hip_runtime.h>
#include <hip/hip_bf16.h>

// Sizes
constexpr int BATCH = 8192;
constexpr int NREAL = 2000;   // real feature / output-col count
constexpr int KSLOT = 2048;   // per-matrix padded K slot
constexpr int KPAD  = 6144;   // 3 * 2048
constexpr int NPAD  = 2048;   // padded N (W_cat rows)
constexpr int NT    = KPAD / 64;  // 96 K-tiles of 64

typedef short bf16x8 __attribute__((ext_vector_type(8)));
typedef float f32x16 __attribute__((ext_vector_type(16)));

__device__ inline void gload_lds16(const void* g, void* l) {
  __builtin_amdgcn_global_load_lds(
      (const __attribute__((address_space(1))) unsigned int*)g,
      (__attribute__((address_space(3))) unsigned int*)l,
      16, 0, 0);
}

__device__ inline unsigned short f2bf(float x) {
  union { float f; unsigned int u; } v;
  v.f = x;
  unsigned int r = v.u + 0x7fffu + ((v.u >> 16) & 1u);
  return (unsigned short)(r >> 16);
}

// ---------------------------------------------------------------------------
// Kernel 1: fused pack. blockIdx.x < 8192: standardize (ddof=1) activations
// into A_cat [8192][6144]; else weight-concat rows into W_cat [2048][6144].
// grid (8192+2048, 3), block 256.
// ---------------------------------------------------------------------------
__global__ __launch_bounds__(256) void pack_kernel(
    const float* __restrict__ prev, const float* __restrict__ nxt,
    const float* __restrict__ selfa,
    const float* __restrict__ fW, const float* __restrict__ bW,
    const float* __restrict__ lW,
    unsigned short* __restrict__ Acat, unsigned short* __restrict__ Wcat) {
  const int mat = blockIdx.y;
  const int t = threadIdx.x;

  if (blockIdx.x >= BATCH) {
    // ---- weight pack ----
    const int s = blockIdx.x - BATCH;
    uint4 q = make_uint4(0, 0, 0, 0);
    if (s < NREAL && t < 250) {
      const float* src = ((mat == 0) ? fW : (mat == 1) ? bW : lW) +
                         (size_t)s * NREAL + t * 8;
      const float4* p = (const float4*)src;
      float4 a = p[0], b = p[1];
      q.x = (unsigned)f2bf(a.x) | ((unsigned)f2bf(a.y) << 16);
      q.y = (unsigned)f2bf(a.z) | ((unsigned)f2bf(a.w) << 16);
      q.z = (unsigned)f2bf(b.x) | ((unsigned)f2bf(b.y) << 16);
      q.w = (unsigned)f2bf(b.z) | ((unsigned)f2bf(b.w) << 16);
    }
    *(uint4*)(Wcat + (size_t)s * KPAD + mat * KSLOT + t * 8) = q;
    return;
  }

  // ---- standardize pack ----
  __shared__ float red[4];
  const int row = blockIdx.x;
  const float* src = (mat == 0) ? prev : (mat == 1) ? nxt : selfa;

  float x[8];
  float s1 = 0.f;
  if (t < 250) {
    const float4* p = (const float4*)(src + (size_t)row * NREAL + t * 8);
    float4 a = p[0], b = p[1];
    x[0] = a.x; x[1] = a.y; x[2] = a.z; x[3] = a.w;
    x[4] = b.x; x[5] = b.y; x[6] = b.z; x[7] = b.w;
#pragma unroll
    for (int j = 0; j < 8; ++j) s1 += x[j];
  } else {
#pragma unroll
    for (int j = 0; j < 8; ++j) x[j] = 0.f;
  }
#pragma unroll
  for (int o = 32; o; o >>= 1) s1 += __shfl_xor(s1, o);
  if ((t & 63) == 0) red[t >> 6] = s1;
  __syncthreads();
  const float mean = (red[0] + red[1] + red[2] + red[3]) * (1.f / 2000.f);
  __syncthreads();

  float ss = 0.f;
  if (t < 250) {
#pragma unroll
    for (int j = 0; j < 8; ++j) { float d = x[j] - mean; ss += d * d; }
  }
#pragma unroll
  for (int o = 32; o; o >>= 1) ss += __shfl_xor(ss, o);
  if ((t & 63) == 0) red[t >> 6] = ss;
  __syncthreads();
  const float var = (red[0] + red[1] + red[2] + red[3]) * (1.f / 1999.f);
  const float scale = 1.f / (sqrtf(var) + 1e-8f);

  unsigned short o8[8];
  if (t < 250) {
#pragma unroll
    for (int j = 0; j < 8; ++j) o8[j] = f2bf((x[j] - mean) * scale);
  } else {
#pragma unroll
    for (int j = 0; j < 8; ++j) o8[j] = 0;
  }
  uint4 q;
  q.x = (unsigned)o8[0] | ((unsigned)o8[1] << 16);
  q.y = (unsigned)o8[2] | ((unsigned)o8[3] << 16);
  q.z = (unsigned)o8[4] | ((unsigned)o8[5] << 16);
  q.w = (unsigned)o8[6] | ((unsigned)o8[7] << 16);
  *(uint4*)(Acat + (size_t)row * KPAD + mat * KSLOT + t * 8) = q;
}

// ---------------------------------------------------------------------------
// Kernel 2: 256x256 bf16 GEMM with 32x32x16 MFMA, 8 waves (2M x 4N),
// 128x64/wave = acc[4][2] f32x16. Minimal sync: ONE vmcnt(0) (all loads a
// full tile old -> free) + ONE barrier per K-tile; NO sched_barrier / lgkm
// asm inside the tile -- compiler pipelines {6 b128 reads -> 8 MFMA} per
// kg-group freely (its proven strength). Staging machinery + XOR swizzle
// identical to R9 (0 conflicts). LDS [buf][mat][kq][256][32], dbuf 128 KiB.
// grid 256 (= 32 bm x 8 bn), block 512.
// ---------------------------------------------------------------------------
__global__ __launch_bounds__(512, 2) void gemm_kernel(
    const unsigned short* __restrict__ A,   // [8192][6144] bf16
    const unsigned short* __restrict__ W,   // [2048][6144] bf16
    const float* __restrict__ fb, const float* __restrict__ bb,
    const float* __restrict__ lb,
    const float* __restrict__ selfact,      // [8192][2000] f32
    float* __restrict__ out) {              // [8192][2000] f32
  __shared__ unsigned short ldsS[2][2][2][256][32];  // 128 KiB
  unsigned short* ldsF = &ldsS[0][0][0][0][0];

  const int tid  = threadIdx.x;
  const int wave = tid >> 6;
  const int lane = tid & 63;
  const int wm = wave >> 2;     // 0..1
  const int wn = wave & 3;      // 0..3

  // XCD-aware block swizzle (256 blocks, 8 XCDs, 32/XCD, 4 bm-panels each)
  const int nbid = (blockIdx.x & 7) * 32 + (blockIdx.x >> 3);
  const int bm = nbid >> 3;     // 0..31
  const int bn = nbid & 7;      // 0..7

  // staging per-thread source (inverse swizzle): srow=tid>>2 (row within
  // 128-row half), physical chunk = lane&3 holds logical chunk sc
  const int srow = tid >> 2;
  const int sc = (tid & 3) ^ ((tid >> 3) & 3);
  const unsigned short* Asrc =
      A + (size_t)(bm * 256 + srow) * KPAD + sc * 8;
  const unsigned short* Bsrc =
      W + (size_t)(bn * 256 + srow) * KPAD + sc * 8;

  // ---- 32x32x16 fragment read offsets (shorts), swizzle folded ----
  // lane reads M[row = grp*32 + (lane&31)][k = kq*32 + (kg&1)*16 + (lane>>5)*8]
  // c_log = (kg&1)*2 + (lane>>5); c_phys = c_log ^ ((row>>1)&3)
  // off(kg) = base ^ ((kg&1)<<4), + (kg>>1)*8192 region step
  const int h = lane >> 5;
  const int l31 = lane & 31;
  int aOff[4], bOff[2];
#pragma unroll
  for (int rg = 0; rg < 4; ++rg) {
    const int row = wm * 128 + rg * 32 + l31;
    aOff[rg] = row * 32 + ((h ^ ((row >> 1) & 3)) << 3);
  }
#pragma unroll
  for (int cg = 0; cg < 2; ++cg) {
    const int row = wn * 64 + cg * 32 + l31;
    bOff[cg] = row * 32 + ((h ^ ((row >> 1) & 3)) << 3);
  }

  f32x16 acc[4][2] = {};

  // stage one kk-quarter of one row-half (1 gload/thread)
#define STQ(bu, mat, kq, rh, tt) { \
    const unsigned short* g_ = ((mat) ? Bsrc : Asrc) + \
        (size_t)(rh) * 128 * KPAD + (size_t)(tt) * 64 + (kq) * 32; \
    unsigned short* d_ = ldsF + ((bu) * 4 + (mat) * 2 + (kq)) * 8192 + \
        (rh) * 4096 + wave * 512; \
    gload_lds16(g_, d_); \
  }
#define STAGE_TILE(bu, tt) { \
    STQ(bu, 0, 0, 0, tt) STQ(bu, 0, 1, 0, tt) \
    STQ(bu, 0, 0, 1, tt) STQ(bu, 0, 1, 1, tt) \
    STQ(bu, 1, 0, 0, tt) STQ(bu, 1, 1, 0, tt) \
    STQ(bu, 1, 0, 1, tt) STQ(bu, 1, 1, 1, tt) }

  // Prologue: stage tile 0; publish.
  STAGE_TILE(0, 0)
  asm volatile("s_waitcnt vmcnt(0)" ::: "memory");
  __builtin_amdgcn_s_barrier();
  __builtin_amdgcn_sched_barrier(0);

  for (int t = 0; t < NT; ++t) {
    const int q = t & 1;
    if (t + 1 < NT) STAGE_TILE(q ^ 1, t + 1)
    const unsigned short* aB = ldsF + (q * 4 + 0) * 8192;
    const unsigned short* bB = ldsF + (q * 4 + 2) * 8192;
#pragma unroll
    for (int kg = 0; kg < 4; ++kg) {
      const int reg = (kg >> 1) * 8192;
      const int kx = (kg & 1) << 4;
      bf16x8 a0 = *(const bf16x8*)(aB + reg + (aOff[0] ^ kx));
      bf16x8 a1 = *(const bf16x8*)(aB + reg + (aOff[1] ^ kx));
      bf16x8 a2 = *(const bf16x8*)(aB + reg + (aOff[2] ^ kx));
      bf16x8 a3 = *(const bf16x8*)(aB + reg + (aOff[3] ^ kx));
      bf16x8 b0 = *(const bf16x8*)(bB + reg + (bOff[0] ^ kx));
      bf16x8 b1 = *(const bf16x8*)(bB + reg + (bOff[1] ^ kx));
      __builtin_amdgcn_s_setprio(1);
      acc[0][0] = __builtin_amdgcn_mfma_f32_32x32x16_bf16(a0, b0, acc[0][0], 0, 0, 0);
      acc[0][1] = __builtin_amdgcn_mfma_f32_32x32x16_bf16(a0, b1, acc[0][1], 0, 0, 0);
      acc[1][0] = __builtin_amdgcn_mfma_f32_32x32x16_bf16(a1, b0, acc[1][0], 0, 0, 0);
      acc[1][1] = __builtin_amdgcn_mfma_f32_32x32x16_bf16(a1, b1, acc[1][1], 0, 0, 0);
      acc[2][0] = __builtin_amdgcn_mfma_f32_32x32x16_bf16(a2, b0, acc[2][0], 0, 0, 0);
      acc[2][1] = __builtin_amdgcn_mfma_f32_32x32x16_bf16(a2, b1, acc[2][1], 0, 0, 0);
      acc[3][0] = __builtin_amdgcn_mfma_f32_32x32x16_bf16(a3, b0, acc[3][0], 0, 0, 0);
      acc[3][1] = __builtin_amdgcn_mfma_f32_32x32x16_bf16(a3, b1, acc[3][1], 0, 0, 0);
      __builtin_amdgcn_s_setprio(0);
    }
    // single sync point per tile: all outstanding gloads are ~1 tile old.
    asm volatile("s_waitcnt vmcnt(0)" ::: "memory");
    __builtin_amdgcn_s_barrier();
    __builtin_amdgcn_sched_barrier(0);
  }

  // Epilogue: 32x32 C/D layout col=lane&31, row=(r&3)+8*(r>>2)+4*(lane>>5)
  const int colBase = bn * 256 + wn * 64 + l31;
  const int rowBase = bm * 256 + wm * 128 + 4 * h;
#pragma unroll
  for (int cg = 0; cg < 2; ++cg) {
    const int col = colBase + cg * 32;
    if (col < NREAL) {
      const float bias = fb[col] + bb[col] + lb[col];
#pragma unroll
      for (int rg = 0; rg < 4; ++rg) {
#pragma unroll
        for (int r = 0; r < 16; ++r) {
          const int row = rowBase + rg * 32 + (r & 3) + 8 * (r >> 2);
          const size_t oi = (size_t)row * NREAL + col;
          const float pre = acc[rg][cg][r] + bias;
          out[oi] = 0.7f * fmaxf(pre, 0.f) + 0.3f * selfact[oi];
        }
      }
    }
  }
#undef STAGE_TILE
#undef STQ
}

// ---------------------------------------------------------------------------
extern "C" void kernel_launch(void* const* d_in, const int* in_sizes, int n_in,
                              void* d_out, int out_size, void* d_ws,
                              size_t ws_size, hipStream_t stream) {
  const float* prev = (const float*)d_in[0];
  const float* selfa = (const float*)d_in[1];
  const float* nxt  = (const float*)d_in[2];
  const float* fW = (const float*)d_in[3];
  const float* fb = (const float*)d_in[4];
  const float* bW = (const float*)d_in[5];
  const float* bb = (const float*)d_in[6];
  const float* lW = (const float*)d_in[7];
  const float* lb = (const float*)d_in[8];
  float* out = (float*)d_out;

  unsigned short* Acat = (unsigned short*)d_ws;                 // 100.7 MB
  unsigned short* Wcat = Acat + (size_t)BATCH * KPAD;           // +25.2 MB

  pack_kernel<<<dim3(BATCH + NPAD, 3), 256, 0, stream>>>(
      prev, nxt, selfa, fW, bW, lW, Acat, Wcat);
  gemm_kernel<<<dim3(32 * 8), 512, 0, stream>>>(Acat, Wcat, fb, bb, lb,
                                                selfa, out);
}